// Round 8
// baseline (648.593 us; speedup 1.0000x reference)
//
#include <hip/hip_runtime.h>

typedef unsigned short ushort_t;
typedef short short8 __attribute__((ext_vector_type(8)));
typedef float f32x4 __attribute__((ext_vector_type(4)));
typedef unsigned short ushort4v __attribute__((ext_vector_type(4)));

// ---------- helpers ----------
__device__ __forceinline__ ushort_t f2bf(float f) {
    unsigned int u = __float_as_uint(f);
    u = (u + 0x7fffu + ((u >> 16) & 1u)) >> 16;
    return (ushort_t)u;
}

__device__ __forceinline__ void async16(void* lds, const void* g) {
    __builtin_amdgcn_global_load_lds(
        (const __attribute__((address_space(1))) unsigned int*)g,
        (__attribute__((address_space(3))) unsigned int*)lds, 16, 0, 0);
}

// ---------- prep kernels ----------
__global__ void conv_x_kernel(const float* __restrict__ in, ushort_t* __restrict__ out) {
    int i = blockIdx.x * 256 + threadIdx.x;      // grid sized exactly: 50176*256 = 12845056
    float4 v = ((const float4*)in)[i];
    ushort4v o;
    o.x = f2bf(v.x); o.y = f2bf(v.y); o.z = f2bf(v.z); o.w = f2bf(v.w);
    ((ushort4v*)out)[i] = o;
}

__global__ void prep_weights(const float* __restrict__ qkv_w, const float* __restrict__ proj_w,
                             ushort_t* __restrict__ wtq, ushort_t* __restrict__ wtp) {
    int o = blockIdx.x * 256 + threadIdx.x;      // grid 3072*256 = 786432
    if (o < 1536 * 512) {
        int n = o >> 9, k = o & 511;
        wtq[o] = f2bf(qkv_w[k * 1536 + n]);      // wtq[n][k] = W[k][n]
    }
    if (o < 512 * 512) {
        int n = o >> 9, k = o & 511;
        wtp[o] = f2bf(proj_w[k * 512 + n]);
    }
}

__global__ void build_cm(const float* __restrict__ mask, const float* __restrict__ rel_table,
                         const int* __restrict__ rel_index, float* __restrict__ cm) {
    int o = blockIdx.x * 256 + threadIdx.x;      // grid 16384*256 = 4194304 = 64*16*64*64
    int c = o & 63, r = (o >> 6) & 63, h = (o >> 12) & 15, w = o >> 16;
    float v = -30000.0f;
    if (r < 49 && c < 49)
        v = rel_table[rel_index[r * 49 + c] * 16 + h] + mask[w * 2401 + r * 49 + c];
    cm[o] = v;
}

// ---------- 256x256 bf16 GEMM: true 8-phase / K-half-staged schedule ----------
// C[M][N] = A[M][K] * Bt[N][K]^T + bias. BM=BN=256, BK=64, 8 waves (2M x 4N).
// LDS: per-matrix per-buf per-K-half buffers [2][2][256x32] bf16 = 128 KiB.
// Iteration computes tiles (t,t+1); 8 phases; EACH phase = {4-8 ds_read_b128
// (bf reused across the mh pair) | 1 K-half stage (2 gloads) | VM8 (counted,
// never 0 in steady state) | barrier | lgkmcnt(0) | 16 MFMA | barrier}.
// Stage schedule (lead 5-6 phases, verified dead-half ledger):
//  ph1:(t+1).A.kh1  ph2:(t+1).B.kh1  ph3:(t+2).A.kh0  ph4:(t+2).B.kh0
//  ph5:(t+2).A.kh1  ph6:(t+2).B.kh1  ph7:(t+3).A.kh0  ph8:(t+3).B.kh0
// VM8/phase completes pairs <= p-4 (read earliest at p+5): exact cover. WAR:
// a half's last ds_reads finish before that phase's END barrier; its re-stage
// is issued after it. Tail iteration: stages ph1-2 only + VM0 at ph6.
// Swizzle: 2-bit chunk XOR (row>>1)&3 on global source AND ds_read (rule 21)
// -> uniform 8 accesses/bank = b128 floor.

#define STAGEH(ldsbase, gbase) do {                                             \
    _Pragma("unroll")                                                           \
    for (int j_ = 0; j_ < 2; ++j_) {                                            \
        const int idx_ = j_ * 512 + tid;                                        \
        const int row_ = idx_ >> 2;                                             \
        const int sw_  = (idx_ & 3) ^ ((row_ >> 1) & 3);                        \
        async16((char*)(ldsbase) + idx_ * 16, (gbase) + (size_t)row_ * K + sw_ * 8); \
    }                                                                           \
} while (0)

#define VM8 asm volatile("s_waitcnt vmcnt(8)" ::: "memory")
#define VM0 asm volatile("s_waitcnt vmcnt(0)" ::: "memory")
#define NOSTG ((void)0)

#define PH(AB, BB, mh, LOADBF, STG, VMW) do {                                   \
    if (LOADBF) {                                                               \
        _Pragma("unroll")                                                       \
        for (int g_ = 0; g_ < 4; ++g_) {                                        \
            const int br_ = wc + g_ * 16 + lr;                                  \
            bf[g_] = *(const short8*)&(BB)[br_ * 32 + ((lk ^ ((br_ >> 1) & 3)) << 3)]; \
        }                                                                       \
    }                                                                           \
    _Pragma("unroll")                                                           \
    for (int f_ = 0; f_ < 4; ++f_) {                                            \
        const int ar_ = wr + (mh) * 64 + f_ * 16 + lr;                          \
        af[f_] = *(const short8*)&(AB)[ar_ * 32 + ((lk ^ ((ar_ >> 1) & 3)) << 3)]; \
    }                                                                           \
    STG;                                                                        \
    VMW;                                                                        \
    __builtin_amdgcn_s_barrier();                                               \
    asm volatile("s_waitcnt lgkmcnt(0)" ::: "memory");                          \
    __builtin_amdgcn_sched_barrier(0);                                          \
    __builtin_amdgcn_s_setprio(1);                                              \
    _Pragma("unroll")                                                           \
    for (int f_ = 0; f_ < 4; ++f_)                                              \
        _Pragma("unroll")                                                       \
        for (int g_ = 0; g_ < 4; ++g_)                                          \
            acc[(mh) * 4 + f_][g_] = __builtin_amdgcn_mfma_f32_16x16x32_bf16(   \
                bf[g_], af[f_], acc[(mh) * 4 + f_][g_], 0, 0, 0);               \
    __builtin_amdgcn_s_setprio(0);                                              \
    __builtin_amdgcn_s_barrier();                                               \
} while (0)

template<int NB_N, int NSTR, bool QKV, int K>
__global__ __launch_bounds__(512, 2)
void gemm8(const ushort_t* __restrict__ A, const ushort_t* __restrict__ Bt,
           const float* __restrict__ bias, void* __restrict__ out)
{
    __shared__ alignas(16) ushort_t As[2][2][256 * 32];   // [buf][khalf]: 64 KiB
    __shared__ alignas(16) ushort_t Bs[2][2][256 * 32];   // 64 KiB

    const int tid = threadIdx.x;
    const int wid = tid >> 6, lane = tid & 63;
    const int lr = lane & 15, lk = lane >> 4;
    const int wr = (wid >> 2) * 128;     // 0 / 128
    const int wc = (wid & 3) * 64;       // 0..192

    // XCD-aware bijective swizzle (grid % 8 == 0 for both GEMMs)
    const int chunk = gridDim.x >> 3;
    const int wg = ((int)blockIdx.x & 7) * chunk + ((int)blockIdx.x >> 3);
    const int nb = wg % NB_N;
    const int mb = wg / NB_N;
    const int m0 = mb << 8, n0 = nb << 8;

    const size_t am = (size_t)m0 * K;    // A panel base (256 rows)
    const size_t bm = (size_t)n0 * K;    // B panel base

    f32x4 acc[8][4];
#pragma unroll
    for (int f = 0; f < 8; ++f)
#pragma unroll
        for (int g = 0; g < 4; ++g)
#pragma unroll
            for (int r = 0; r < 4; ++r) acc[f][g][r] = 0.f;

    // prologue: pairs P1..P6 = t0.Akh0, t0.Bkh0, t0.Akh1, t0.Bkh1, t1.Akh0, t1.Bkh0
    STAGEH(&As[0][0][0], A  + am);
    STAGEH(&Bs[0][0][0], Bt + bm);
    STAGEH(&As[0][1][0], A  + am + 32);
    STAGEH(&Bs[0][1][0], Bt + bm + 32);
    STAGEH(&As[1][0][0], A  + am + 64);
    STAGEH(&Bs[1][0][0], Bt + bm + 64);
    VM8;   // completes P1,P2 (ph1's halves); P3..P6 stay in flight
    __builtin_amdgcn_s_barrier();

    const int NI = K >> 7;   // iterations (2 tiles each); 4 for K=512
    for (int i = 0; i < NI; ++i) {
        const int t = 2 * i;
        const bool more = (i < NI - 1);
        short8 af[4], bf[4];
        // ph1-2: tile t, kh0
        PH(As[0][0], Bs[0][0], 0, true,
           STAGEH(&As[1][1][0], A  + am + (size_t)(t + 1) * 64 + 32), VM8);
        PH(As[0][0], Bs[0][0], 1, false,
           STAGEH(&Bs[1][1][0], Bt + bm + (size_t)(t + 1) * 64 + 32), VM8);
        // ph3-4: tile t, kh1
        PH(As[0][1], Bs[0][1], 0, true,
           if (more) STAGEH(&As[0][0][0], A  + am + (size_t)(t + 2) * 64), VM8);
        PH(As[0][1], Bs[0][1], 1, false,
           if (more) STAGEH(&Bs[0][0][0], Bt + bm + (size_t)(t + 2) * 64), VM8);
        // ph5-6: tile t+1, kh0
        PH(As[1][0], Bs[1][0], 0, true,
           if (more) STAGEH(&As[0][1][0], A  + am + (size_t)(t + 2) * 64 + 32), VM8);
        PH(As[1][0], Bs[1][0], 1, false,
           if (more) STAGEH(&Bs[0][1][0], Bt + bm + (size_t)(t + 2) * 64 + 32),
           do { if (more) { VM8; } else { VM0; } } while (0));   // tail: drain ph1-2 pairs
        // ph7-8: tile t+1, kh1
        PH(As[1][1], Bs[1][1], 0, true,
           if (more) STAGEH(&As[1][0][0], A  + am + (size_t)(t + 3) * 64), VM8);
        PH(As[1][1], Bs[1][1], 1, false,
           if (more) STAGEH(&Bs[1][0][0], Bt + bm + (size_t)(t + 3) * 64), VM8);
    }

    // epilogue: row = m0+wr+f*16+lr, cols = n0+wc+g*16+lk*4 + (0..3)
#pragma unroll
    for (int f = 0; f < 8; ++f) {
        const int row = m0 + wr + f * 16 + lr;
#pragma unroll
        for (int g = 0; g < 4; ++g) {
            const int col = n0 + wc + g * 16 + lk * 4;
            const float4 bv = *(const float4*)&bias[col];
            float v0 = acc[f][g][0] + bv.x;
            float v1 = acc[f][g][1] + bv.y;
            float v2 = acc[f][g][2] + bv.z;
            float v3 = acc[f][g][3] + bv.w;
            if (QKV) {
                if (col < 512) {   // q pre-scale (uniform per 4-col block)
                    v0 *= 0.17677669529663689f; v1 *= 0.17677669529663689f;
                    v2 *= 0.17677669529663689f; v3 *= 0.17677669529663689f;
                }
                ushort4v o;
                o.x = f2bf(v0); o.y = f2bf(v1); o.z = f2bf(v2); o.w = f2bf(v3);
                *(ushort4v*)&((ushort_t*)out)[(size_t)row * NSTR + col] = o;
            } else {
                float4 o; o.x = v0; o.y = v1; o.z = v2; o.w = v3;
                *(float4*)&((float*)out)[(size_t)row * NSTR + col] = o;
            }
        }
    }
}

// ---------- fused window attention: one wave per (b,h) ----------
// qkv: [100352][1536] bf16 (q pre-scaled, bias added). cm: [64][16][64][64] f32.
// out: [100352][512] bf16  (out[b*49+n][h*32+d])
#define PL_STRIDE 80   // bf16 elems; 160B rows -> 16B aligned
#define VT_STRIDE 88   // bf16 elems; 176B rows -> 16B aligned, low bank conflict
__global__ __launch_bounds__(256, 2)
void attn_kernel(const ushort_t* __restrict__ qkv, const float* __restrict__ cm,
                 ushort_t* __restrict__ out)
{
    // Pl region (40960B) is unioned with the cm tile (16640B); vT separate (22528B).
    __shared__ alignas(16) char smem[4 * 64 * PL_STRIDE * 2 + 4 * 32 * VT_STRIDE * 2];
    float* cmf = (float*)smem;                                    // [64][65]
    ushort_t* Pl = (ushort_t*)smem;                               // [4][64][PL_STRIDE]
    ushort_t* vT = (ushort_t*)(smem + 4 * 64 * PL_STRIDE * 2);    // [4][32][VT_STRIDE]

    const int w = blockIdx.x, h = blockIdx.y, ig = blockIdx.z;    // r1 grid (w fastest)
    const int tid = threadIdx.x;
    const int wid = tid >> 6, lane = tid & 63;
    const int lr = lane & 15, lk = lane >> 4;
    const int b = (ig * 4 + wid) * 64 + w;       // b % 64 == w (mask window index)

    // stage cm[w][h] tile into LDS (shared by the 4 waves)
    const float* cmsrc = cm + ((size_t)(w * 16 + h) << 12);
    for (int t = tid; t < 4096; t += 256)
        cmf[(t >> 6) * 65 + (t & 63)] = cmsrc[t];
    __syncthreads();

    const size_t base = (size_t)b * 49 * 1536 + h * 32;

    // q/k fragments (rows padded 49->64 via clamp; garbage killed by cm = -30000)
    short8 aq[4], bk[4];
#pragma unroll
    for (int i = 0; i < 4; ++i) {
        int n = i * 16 + lr; n = n > 48 ? 48 : n;
        aq[i] = *(const short8*)&qkv[base + (size_t)n * 1536 + lk * 8];
    }
#pragma unroll
    for (int j = 0; j < 4; ++j) {
        int m = j * 16 + lr; m = m > 48 ? 48 : m;
        bk[j] = *(const short8*)&qkv[base + 512 + (size_t)m * 1536 + lk * 8];
    }

    f32x4 s[4][4];
#pragma unroll
    for (int i = 0; i < 4; ++i)
#pragma unroll
        for (int j = 0; j < 4; ++j)
#pragma unroll
            for (int r = 0; r < 4; ++r) s[i][j][r] = 0.f;
#pragma unroll
    for (int i = 0; i < 4; ++i)
#pragma unroll
        for (int j = 0; j < 4; ++j)
            s[i][j] = __builtin_amdgcn_mfma_f32_16x16x32_bf16(aq[i], bk[j], s[i][j], 0, 0, 0);

    // v load (row m = lane) and transposed LDS store vT[d][m]
    short8 vv[4];
#pragma unroll
    for (int t = 0; t < 4; ++t)
#pragma unroll
        for (int e = 0; e < 8; ++e) vv[t][e] = 0;
    if (lane < 49) {
        const ushort_t* vp = &qkv[base + 1024 + (size_t)lane * 1536];
#pragma unroll
        for (int t = 0; t < 4; ++t) vv[t] = *(const short8*)(vp + t * 8);
    }
    ushort_t* vTw = vT + wid * 32 * VT_STRIDE;
#pragma unroll
    for (int t = 0; t < 4; ++t)
#pragma unroll
        for (int e = 0; e < 8; ++e)
            vTw[(t * 8 + e) * VT_STRIDE + lane] = (ushort_t)vv[t][e];

    // add bias+mask, wave-parallel softmax (rows are (lk*4+r)+16i, cols lane-spread)
#pragma unroll
    for (int i = 0; i < 4; ++i) {
#pragma unroll
        for (int r = 0; r < 4; ++r) {
            const int row = i * 16 + lk * 4 + r;
            float v0 = s[i][0][r] + cmf[row * 65 + lr];
            float v1 = s[i][1][r] + cmf[row * 65 + 16 + lr];
            float v2 = s[i][2][r] + cmf[row * 65 + 32 + lr];
            float v3 = s[i][3][r] + cmf[row * 65 + 48 + lr];
            float mx = fmaxf(fmaxf(v0, v1), fmaxf(v2, v3));
#pragma unroll
            for (int t = 1; t < 16; t <<= 1) mx = fmaxf(mx, __shfl_xor(mx, t, 64));
            v0 = __expf(v0 - mx); v1 = __expf(v1 - mx);
            v2 = __expf(v2 - mx); v3 = __expf(v3 - mx);
            float sm = v0 + v1 + v2 + v3;
#pragma unroll
            for (int t = 1; t < 16; t <<= 1) sm += __shfl_xor(sm, t, 64);
            const float inv = 1.0f / sm;
            s[i][0][r] = v0 * inv; s[i][1][r] = v1 * inv;
            s[i][2][r] = v2 * inv; s[i][3][r] = v3 * inv;
        }
    }
    __syncthreads();   // all waves done reading cm tile; safe to overwrite with P

    // P -> bf16 -> LDS (per-wave slice)
    ushort_t* Pw = Pl + wid * 64 * PL_STRIDE;
#pragma unroll
    for (int i = 0; i < 4; ++i)
#pragma unroll
        for (int j = 0; j < 4; ++j)
#pragma unroll
            for (int r = 0; r < 4; ++r)
                Pw[(i * 16 + lk * 4 + r) * PL_STRIDE + j * 16 + lr] = f2bf(s[i][j][r]);

    // PV: out[n][d] = sum_m P[n][m] * v[m][d]; operands swapped so each lane
    // holds 4 consecutive d for one n -> packed 8B stores.
    f32x4 o[4][2];
#pragma unroll
    for (int i = 0; i < 4; ++i)
#pragma unroll
        for (int jb = 0; jb < 2; ++jb)
#pragma unroll
            for (int r = 0; r < 4; ++r) o[i][jb][r] = 0.f;
#pragma unroll
    for (int ks = 0; ks < 2; ++ks) {
        short8 pa[4], vb[2];
#pragma unroll
        for (int i = 0; i < 4; ++i)
            pa[i] = *(const short8*)&Pw[(i * 16 + lr) * PL_STRIDE + ks * 32 + lk * 8];
#pragma unroll
        for (int jb = 0; jb < 2; ++jb)
            vb[jb] = *(const short8*)&vTw[(jb * 16 + lr) * VT_STRIDE + ks * 32 + lk * 8];
#pragma unroll
        for (int i = 0; i < 4; ++i)
#pragma unroll
            for (int jb = 0; jb < 2; ++jb)
                o[i][jb] = __builtin_amdgcn_mfma_f32_16x16x32_bf16(vb[jb], pa[i], o[i][jb], 0, 0, 0);
    }

    // write attn output (bf16) as [b*49+n][h*32+d]; n = i*16+lr, d = jb*16+lk*4+(0..3)
    const size_t obase = (size_t)b * 49 * 512 + h * 32;
#pragma unroll
    for (int i = 0; i < 4; ++i) {
        const int n = i * 16 + lr;
        if (n < 49) {
#pragma unroll
            for (int jb = 0; jb < 2; ++jb) {
                ushort4v ov;
                ov.x = f2bf(o[i][jb][0]); ov.y = f2bf(o[i][jb][1]);
                ov.z = f2bf(o[i][jb][2]); ov.w = f2bf(o[i][jb][3]);
                *(ushort4v*)&out[obase + (size_t)n * 512 + jb * 16 + lk * 4] = ov;
            }
        }
    }
}

// ---------- launch ----------
extern "C" void kernel_launch(void* const* d_in, const int* in_sizes, int n_in,
                              void* d_out, int out_size, void* d_ws, size_t ws_size,
                              hipStream_t stream)
{
    const float* x         = (const float*)d_in[0];
    const float* mask      = (const float*)d_in[1];
    const float* qkv_w     = (const float*)d_in[2];
    const float* qkv_b     = (const float*)d_in[3];
    const float* proj_w    = (const float*)d_in[4];
    const float* proj_b    = (const float*)d_in[5];
    const float* rel_table = (const float*)d_in[6];
    const int*   rel_index = (const int*)d_in[7];

    char* ws = (char*)d_ws;
    ushort_t* xb  = (ushort_t*)ws;                      // x bf16 / attn-out reuse: 102,760,448 B
    ushort_t* qkv = (ushort_t*)(ws + 102760448);        // 308,281,344 B
    ushort_t* wtq = (ushort_t*)(ws + 411041792);        // 1,572,864 B
    ushort_t* wtp = (ushort_t*)(ws + 412614656);        // 524,288 B
    float*    cm  = (float*)  (ws + 413138944);         // 16,777,216 B (total ~430 MB)

    conv_x_kernel<<<50176, 256, 0, stream>>>(x, xb);
    prep_weights<<<3072, 256, 0, stream>>>(qkv_w, proj_w, wtq, wtp);
    build_cm<<<16384, 256, 0, stream>>>(mask, rel_table, rel_index, cm);

    // QKV GEMM: [100352,512] x [512,1536] -> qkv bf16 (q pre-scaled); 392x6 tiles
    gemm8<6, 1536, true, 512><<<2352, 512, 0, stream>>>(xb, wtq, qkv_b, qkv);

    // attention: grid (window fast, head, image-group), 4 waves/block
    attn_kernel<<<dim3(64, 16, 8), 256, 0, stream>>>(qkv, cm, xb);

    // proj GEMM: [100352,512] x [512,512] -> d_out f32; 392x2 tiles
    gemm8<2, 512, false, 512><<<784, 512, 0, stream>>>(xb, wtp, proj_b, d_out);
}